// Round 1
// baseline (474.915 us; speedup 1.0000x reference)
//
#include <hip/hip_runtime.h>
#include <hip/hip_bf16.h>

typedef __attribute__((ext_vector_type(8))) short short8;
typedef __attribute__((ext_vector_type(4))) float float4v;

static __device__ __forceinline__ float bf2f(__hip_bfloat16 v) { return __bfloat162float(v); }

// ---------------- CSR build ----------------

__global__ void k_degree(const int* __restrict__ dst, int* __restrict__ deg, int E) {
    int e = blockIdx.x * blockDim.x + threadIdx.x;
    if (e < E) atomicAdd(&deg[dst[e]], 1);
}

__global__ void k_dinv(const int* __restrict__ deg, float* __restrict__ dinv, int n) {
    int i = blockIdx.x * blockDim.x + threadIdx.x;
    if (i < n) dinv[i] = rsqrtf((float)(deg[i] + 1));  // +1 self-loop; always > 0
}

__global__ void k_scan1(const int* __restrict__ deg, int* __restrict__ incl,
                        int* __restrict__ bsum, int n) {
    __shared__ int s[1024];
    int i = blockIdx.x * 1024 + threadIdx.x;
    int v = (i < n) ? deg[i] : 0;
    s[threadIdx.x] = v;
    __syncthreads();
    for (int off = 1; off < 1024; off <<= 1) {
        int t = (threadIdx.x >= off) ? s[threadIdx.x - off] : 0;
        __syncthreads();
        s[threadIdx.x] += t;
        __syncthreads();
    }
    if (i < n) incl[i] = s[threadIdx.x];
    if (threadIdx.x == 1023) bsum[blockIdx.x] = s[1023];
}

__global__ void k_scan2(int* __restrict__ bsum, int nb) {
    __shared__ int s[1024];
    int tid = threadIdx.x;
    int v = (tid < nb) ? bsum[tid] : 0;
    int orig = v;
    s[tid] = v;
    __syncthreads();
    for (int off = 1; off < 1024; off <<= 1) {
        int t = (tid >= off) ? s[tid - off] : 0;
        __syncthreads();
        s[tid] += t;
        __syncthreads();
    }
    if (tid < nb) bsum[tid] = s[tid] - orig;  // exclusive block offsets
}

__global__ void k_scan3(const int* __restrict__ incl, const int* __restrict__ deg,
                        const int* __restrict__ bofs, int* __restrict__ row_ptr,
                        int* __restrict__ cursor, int n) {
    int i = blockIdx.x * blockDim.x + threadIdx.x;
    if (i >= n) return;
    int ex = bofs[i >> 10] + incl[i] - deg[i];
    row_ptr[i] = ex;
    cursor[i] = ex;
    if (i == n - 1) row_ptr[n] = bofs[i >> 10] + incl[i];
}

__global__ void k_csr(const int* __restrict__ src, const int* __restrict__ dst,
                      int* __restrict__ cursor, int* __restrict__ csr_src, int E) {
    int e = blockIdx.x * blockDim.x + threadIdx.x;
    if (e >= E) return;
    int pos = atomicAdd(&cursor[dst[e]], 1);
    csr_src[pos] = src[e];
}

// ---------------- Layer 1: aggregate x (N,9), then matmul 9->512 ----------------

__global__ void k_agg1(const float* __restrict__ x, const float* __restrict__ dinv,
                       const int* __restrict__ row_ptr, const int* __restrict__ csr,
                       float* __restrict__ aggx, int n) {
    int idx = blockIdx.x * blockDim.x + threadIdx.x;
    if (idx >= n * 9) return;
    int node = idx / 9, f = idx - node * 9;
    float di = dinv[node];
    float acc = di * x[idx];  // self-loop (weight dinv^2 after final *di)
    int e0 = row_ptr[node], e1 = row_ptr[node + 1];
    for (int e = e0; e < e1; ++e) {
        int s = csr[e];
        acc += dinv[s] * x[s * 9 + f];
    }
    aggx[idx] = di * acc;
}

__global__ void k_l1mm(const float* __restrict__ agg, const float* __restrict__ W1,
                       const float* __restrict__ b1, __hip_bfloat16* __restrict__ h1, int n) {
    int idx = blockIdx.x * blockDim.x + threadIdx.x;
    if (idx >= n * 512) return;
    int node = idx >> 9, j = idx & 511;
    const float* a = agg + node * 9;
    float acc = b1[j];
#pragma unroll
    for (int f = 0; f < 9; ++f) acc += a[f] * W1[f * 512 + j];
    h1[idx] = __float2bfloat16(fmaxf(acc, 0.f));  // store post-ReLU, bf16
}

// ---------------- Layer 2: bf16 MFMA GEMM [n,512]@[512,128], then gather-agg ----------------

__global__ void k_w2t(const float* __restrict__ W2, __hip_bfloat16* __restrict__ W2t) {
    int idx = blockIdx.x * blockDim.x + threadIdx.x;  // 512*128
    if (idx >= 512 * 128) return;
    int k = idx >> 7, j = idx & 127;
    W2t[j * 512 + k] = __float2bfloat16(W2[idx]);  // W2t[n][k] = B^T
}

// wave computes 16 nodes x 64 cols (4 col-tiles); block = 4 waves = 64 nodes; grid.y = 2 col halves
__global__ __launch_bounds__(256) void k_l2mm(const __hip_bfloat16* __restrict__ h1,
                                              const __hip_bfloat16* __restrict__ W2t,
                                              __hip_bfloat16* __restrict__ t2, int n) {
    int wid = threadIdx.x >> 6, lane = threadIdx.x & 63;
    int tile = blockIdx.x * 4 + wid;
    int ntiles = n >> 4;  // n divisible by 16 (50000/16 = 3125)
    if (tile >= ntiles) return;
    int m0 = tile << 4;
    int colBase = blockIdx.y << 6;
    int r = lane & 15, quad = lane >> 4;

    // A frag: A[m=lane&15][k=quad*8+j]  (m89-verified)
    const short8* ap = reinterpret_cast<const short8*>(h1 + (size_t)(m0 + r) * 512 + quad * 8);
    // B frag: B[k=quad*8+j][nn=lane&15] -> read W2t[nn][k] contiguous
    const short8* bp0 = reinterpret_cast<const short8*>(W2t + (size_t)(colBase + 0  + r) * 512 + quad * 8);
    const short8* bp1 = reinterpret_cast<const short8*>(W2t + (size_t)(colBase + 16 + r) * 512 + quad * 8);
    const short8* bp2 = reinterpret_cast<const short8*>(W2t + (size_t)(colBase + 32 + r) * 512 + quad * 8);
    const short8* bp3 = reinterpret_cast<const short8*>(W2t + (size_t)(colBase + 48 + r) * 512 + quad * 8);

    float4v acc0 = {0, 0, 0, 0}, acc1 = {0, 0, 0, 0}, acc2 = {0, 0, 0, 0}, acc3 = {0, 0, 0, 0};
#pragma unroll
    for (int k0 = 0; k0 < 512; k0 += 32) {
        int ki = k0 >> 3;
        short8 a = ap[ki];
        acc0 = __builtin_amdgcn_mfma_f32_16x16x32_bf16(a, bp0[ki], acc0, 0, 0, 0);
        acc1 = __builtin_amdgcn_mfma_f32_16x16x32_bf16(a, bp1[ki], acc1, 0, 0, 0);
        acc2 = __builtin_amdgcn_mfma_f32_16x16x32_bf16(a, bp2[ki], acc2, 0, 0, 0);
        acc3 = __builtin_amdgcn_mfma_f32_16x16x32_bf16(a, bp3[ki], acc3, 0, 0, 0);
    }
    // C/D: col = lane&15, row = quad*4 + reg  (m89-verified)
#pragma unroll
    for (int i = 0; i < 4; ++i) {
        size_t node = (size_t)(m0 + quad * 4 + i);
        int col = colBase + r;
        t2[node * 128 + col + 0]  = __float2bfloat16(acc0[i]);
        t2[node * 128 + col + 16] = __float2bfloat16(acc1[i]);
        t2[node * 128 + col + 32] = __float2bfloat16(acc2[i]);
        t2[node * 128 + col + 48] = __float2bfloat16(acc3[i]);
    }
}

__global__ void k_agg2(const __hip_bfloat16* __restrict__ t2, const float* __restrict__ dinv,
                       const int* __restrict__ row_ptr, const int* __restrict__ csr,
                       const float* __restrict__ b2, float* __restrict__ h2, int n) {
    int node = blockIdx.x * 2 + (threadIdx.x >> 7);
    int f = threadIdx.x & 127;
    if (node >= n) return;
    float di = dinv[node];
    float acc = di * bf2f(t2[(size_t)node * 128 + f]);
    int e0 = row_ptr[node], e1 = row_ptr[node + 1];
    for (int e = e0; e < e1; ++e) {
        int s = csr[e];
        acc += dinv[s] * bf2f(t2[(size_t)s * 128 + f]);
    }
    h2[(size_t)node * 128 + f] = fmaxf(di * acc + b2[f], 0.f);
}

// ---------------- Layer 3: matmul 128->2, gather-agg + log_softmax ----------------

__global__ void k_l3mm(const float* __restrict__ h2, const float* __restrict__ W3,
                       float* __restrict__ t3, int n) {
    __shared__ float w[256];
    w[threadIdx.x] = W3[threadIdx.x & 255];
    __syncthreads();
    int node = blockIdx.x * blockDim.x + threadIdx.x;
    if (node >= n) return;
    const float* h = h2 + (size_t)node * 128;
    float a0 = 0.f, a1 = 0.f;
#pragma unroll
    for (int k = 0; k < 128; ++k) {
        float v = h[k];
        a0 += v * w[k * 2];
        a1 += v * w[k * 2 + 1];
    }
    t3[node * 2] = a0;
    t3[node * 2 + 1] = a1;
}

__global__ void k_agg3(const float* __restrict__ t3, const float* __restrict__ dinv,
                       const int* __restrict__ row_ptr, const int* __restrict__ csr,
                       const float* __restrict__ b3, float* __restrict__ out, int n) {
    int idx = blockIdx.x * blockDim.x + threadIdx.x;
    if (idx >= n * 2) return;
    int node = idx >> 1, c = idx & 1;
    float di = dinv[node];
    float acc = di * t3[idx];
    int e0 = row_ptr[node], e1 = row_ptr[node + 1];
    for (int e = e0; e < e1; ++e) {
        int s = csr[e];
        acc += dinv[s] * t3[s * 2 + c];
    }
    float z = di * acc + b3[c];
    float zo = __shfl_xor(z, 1);
    float m = fmaxf(z, zo);
    float lse = m + logf(expf(z - m) + expf(zo - m));
    out[idx] = z - lse;
}

// ---------------- launch ----------------

extern "C" void kernel_launch(void* const* d_in, const int* in_sizes, int n_in,
                              void* d_out, int out_size, void* d_ws, size_t ws_size,
                              hipStream_t stream) {
    const float* x  = (const float*)d_in[0];
    const float* W1 = (const float*)d_in[1];
    const float* b1 = (const float*)d_in[2];
    const float* W2 = (const float*)d_in[3];
    const float* b2 = (const float*)d_in[4];
    const float* W3 = (const float*)d_in[5];
    const float* b3 = (const float*)d_in[6];
    const int* edges = (const int*)d_in[7];

    int n = in_sizes[0] / 9;
    int E = in_sizes[7] / 2;
    const int* src = edges;
    const int* dst = edges + E;
    float* out = (float*)d_out;

    char* p = (char*)d_ws;
    auto alloc = [&](size_t bytes) {
        char* q = p;
        p += (bytes + 511) & ~(size_t)511;
        return q;
    };
    int*   deg     = (int*)alloc((size_t)n * 4);
    float* dinv    = (float*)alloc((size_t)n * 4);
    int*   incl    = (int*)alloc((size_t)n * 4);
    int*   bsum    = (int*)alloc(4096);
    int*   row_ptr = (int*)alloc((size_t)(n + 1) * 4);
    int*   cursor  = (int*)alloc((size_t)n * 4);
    int*   csr     = (int*)alloc((size_t)E * 4);
    float* aggx    = (float*)alloc((size_t)n * 9 * 4);
    __hip_bfloat16* h1  = (__hip_bfloat16*)alloc((size_t)n * 512 * 2);
    __hip_bfloat16* W2t = (__hip_bfloat16*)alloc(512 * 128 * 2);
    __hip_bfloat16* t2  = (__hip_bfloat16*)alloc((size_t)n * 128 * 2);
    float* h2 = (float*)alloc((size_t)n * 128 * 4);
    float* t3 = (float*)alloc((size_t)n * 2 * 4);

    const int B = 256;
    hipMemsetAsync(deg, 0, (size_t)n * 4, stream);
    k_degree<<<(E + B - 1) / B, B, 0, stream>>>(dst, deg, E);
    k_dinv<<<(n + B - 1) / B, B, 0, stream>>>(deg, dinv, n);
    int nb = (n + 1023) / 1024;
    k_scan1<<<nb, 1024, 0, stream>>>(deg, incl, bsum, n);
    k_scan2<<<1, 1024, 0, stream>>>(bsum, nb);
    k_scan3<<<(n + B - 1) / B, B, 0, stream>>>(incl, deg, bsum, row_ptr, cursor, n);
    k_csr<<<(E + B - 1) / B, B, 0, stream>>>(src, dst, cursor, csr, E);

    k_agg1<<<(n * 9 + B - 1) / B, B, 0, stream>>>(x, dinv, row_ptr, csr, aggx, n);
    k_l1mm<<<(n * 512 + B - 1) / B, B, 0, stream>>>(aggx, W1, b1, h1, n);

    k_w2t<<<(512 * 128 + B - 1) / B, B, 0, stream>>>(W2, W2t);
    dim3 g2((n / 16 + 3) / 4, 2);
    k_l2mm<<<g2, 256, 0, stream>>>(h1, W2t, t2, n);
    k_agg2<<<(n + 1) / 2, 256, 0, stream>>>(t2, dinv, row_ptr, csr, b2, h2, n);

    k_l3mm<<<(n + B - 1) / B, B, 0, stream>>>(h2, W3, t3, n);
    k_agg3<<<(n * 2 + B - 1) / B, B, 0, stream>>>(t3, dinv, row_ptr, csr, b3, out, n);
}

// Round 2
// 330.319 us; speedup vs baseline: 1.4377x; 1.4377x over previous
//
#include <hip/hip_runtime.h>
#include <hip/hip_bf16.h>

typedef __attribute__((ext_vector_type(8))) short short8;
typedef __attribute__((ext_vector_type(4))) float float4v;
typedef unsigned int uint;

static __device__ __forceinline__ float2 up_bf2(uint v) {
    float2 r;
    r.x = __uint_as_float(v << 16);
    r.y = __uint_as_float(v & 0xffff0000u);
    return r;
}
static __device__ __forceinline__ short f2bf_bits(float x) {
    union { __hip_bfloat16 h; short s; } u;
    u.h = __float2bfloat16(x);
    return u.s;
}

// ---------------- CSR build ----------------

__global__ void k_degree(const int* __restrict__ dst, int* __restrict__ deg, int E) {
    int e = blockIdx.x * blockDim.x + threadIdx.x;
    if (e < E) atomicAdd(&deg[dst[e]], 1);
}

__global__ void k_dinv(const int* __restrict__ deg, float* __restrict__ dinv, int n) {
    int i = blockIdx.x * blockDim.x + threadIdx.x;
    if (i < n) dinv[i] = rsqrtf((float)(deg[i] + 1));  // +1 self-loop; always > 0
}

__global__ void k_scan1(const int* __restrict__ deg, int* __restrict__ incl,
                        int* __restrict__ bsum, int n) {
    __shared__ int s[1024];
    int i = blockIdx.x * 1024 + threadIdx.x;
    int v = (i < n) ? deg[i] : 0;
    s[threadIdx.x] = v;
    __syncthreads();
    for (int off = 1; off < 1024; off <<= 1) {
        int t = (threadIdx.x >= off) ? s[threadIdx.x - off] : 0;
        __syncthreads();
        s[threadIdx.x] += t;
        __syncthreads();
    }
    if (i < n) incl[i] = s[threadIdx.x];
    if (threadIdx.x == 1023) bsum[blockIdx.x] = s[1023];
}

__global__ void k_scan2(int* __restrict__ bsum, int nb) {
    __shared__ int s[1024];
    int tid = threadIdx.x;
    int v = (tid < nb) ? bsum[tid] : 0;
    int orig = v;
    s[tid] = v;
    __syncthreads();
    for (int off = 1; off < 1024; off <<= 1) {
        int t = (tid >= off) ? s[tid - off] : 0;
        __syncthreads();
        s[tid] += t;
        __syncthreads();
    }
    if (tid < nb) bsum[tid] = s[tid] - orig;  // exclusive block offsets
}

__global__ void k_scan3(const int* __restrict__ incl, const int* __restrict__ deg,
                        const int* __restrict__ bofs, int* __restrict__ row_ptr,
                        int* __restrict__ cursor, int n) {
    int i = blockIdx.x * blockDim.x + threadIdx.x;
    if (i >= n) return;
    int ex = bofs[i >> 10] + incl[i] - deg[i];
    row_ptr[i] = ex;
    cursor[i] = ex;
    if (i == n - 1) row_ptr[n] = bofs[i >> 10] + incl[i];
}

// builds packed edge list: ew[pos] = {src, bits(dinv[src])}
__global__ void k_csr(const int* __restrict__ src, const int* __restrict__ dst,
                      const float* __restrict__ dinv,
                      int* __restrict__ cursor, int2* __restrict__ ew, int E) {
    int e = blockIdx.x * blockDim.x + threadIdx.x;
    if (e >= E) return;
    int s = src[e];
    int pos = atomicAdd(&cursor[dst[e]], 1);
    ew[pos] = make_int2(s, __float_as_int(dinv[s]));
}

// ---------------- Layer 1: aggregate x (N,9), then matmul 9->512 ----------------

// 16-lane group per node; lane f<9 handles feature f; unrolled packed-edge loop
__global__ __launch_bounds__(256) void k_agg1(const float* __restrict__ x,
                       const float* __restrict__ dinv,
                       const int* __restrict__ row_ptr, const int2* __restrict__ ew,
                       float* __restrict__ aggx, int n) {
    int node = blockIdx.x * 16 + (threadIdx.x >> 4);
    if (node >= n) return;
    int f = threadIdx.x & 15;
    bool act = f < 9;
    float di = dinv[node];
    float acc = act ? di * x[node * 9 + f] : 0.f;  // self-loop
    int e0 = row_ptr[node], e1 = row_ptr[node + 1];
    int e = e0;
    for (; e + 2 <= e1; e += 2) {
        int2 wA = ew[e], wB = ew[e + 1];
        float xa = act ? x[wA.x * 9 + f] : 0.f;
        float xb = act ? x[wB.x * 9 + f] : 0.f;
        acc += __int_as_float(wA.y) * xa + __int_as_float(wB.y) * xb;
    }
    if (e < e1) {
        int2 wA = ew[e];
        float xa = act ? x[wA.x * 9 + f] : 0.f;
        acc += __int_as_float(wA.y) * xa;
    }
    if (act) aggx[node * 9 + f] = di * acc;
}

// 8 outputs per thread, short8 (16B) stores
__global__ void k_l1mm(const float* __restrict__ agg, const float* __restrict__ W1,
                       const float* __restrict__ b1, __hip_bfloat16* __restrict__ h1, int n) {
    int t = blockIdx.x * blockDim.x + threadIdx.x;
    if (t >= n * 64) return;
    int node = t >> 6, j0 = (t & 63) << 3;
    const float* a = agg + node * 9;
    float av[9];
#pragma unroll
    for (int f = 0; f < 9; ++f) av[f] = a[f];
    float acc[8];
#pragma unroll
    for (int j = 0; j < 8; ++j) acc[j] = b1[j0 + j];
#pragma unroll
    for (int f = 0; f < 9; ++f)
#pragma unroll
        for (int j = 0; j < 8; ++j) acc[j] += av[f] * W1[f * 512 + j0 + j];
    short8 o;
#pragma unroll
    for (int j = 0; j < 8; ++j) o[j] = f2bf_bits(fmaxf(acc[j], 0.f));
    *reinterpret_cast<short8*>(h1 + (size_t)node * 512 + j0) = o;
}

// ---------------- Layer 2: bf16 MFMA GEMM [n,512]@[512,128] ----------------

__global__ void k_w2t(const float* __restrict__ W2, __hip_bfloat16* __restrict__ W2t) {
    int idx = blockIdx.x * blockDim.x + threadIdx.x;  // 512*128
    if (idx >= 512 * 128) return;
    int k = idx >> 7, j = idx & 127;
    W2t[j * 512 + k] = __float2bfloat16(W2[idx]);  // W2t[n][k] = B^T
}

// wave computes 16 nodes x all 128 cols (8 col-tiles); block = 4 waves = 64 nodes
__global__ __launch_bounds__(256) void k_l2mm(const __hip_bfloat16* __restrict__ h1,
                                              const __hip_bfloat16* __restrict__ W2t,
                                              __hip_bfloat16* __restrict__ t2, int n) {
    int wid = threadIdx.x >> 6, lane = threadIdx.x & 63;
    int tile = blockIdx.x * 4 + wid;
    int ntiles = n >> 4;  // n divisible by 16
    if (tile >= ntiles) return;
    int m0 = tile << 4;
    int r = lane & 15, quad = lane >> 4;

    // A frag: A[m=lane&15][k=quad*8+j]
    const short8* ap = reinterpret_cast<const short8*>(h1 + (size_t)(m0 + r) * 512 + quad * 8);
    // B frags: B[k][nn=lane&15] from W2t[col][k]
    const short8* bp = reinterpret_cast<const short8*>(W2t + (size_t)r * 512 + quad * 8);

    float4v acc[8];
#pragma unroll
    for (int c = 0; c < 8; ++c) acc[c] = (float4v){0, 0, 0, 0};
#pragma unroll
    for (int k0 = 0; k0 < 512; k0 += 32) {
        int ki = k0 >> 3;
        short8 a = ap[ki];
#pragma unroll
        for (int c = 0; c < 8; ++c)
            acc[c] = __builtin_amdgcn_mfma_f32_16x16x32_bf16(a, bp[ki + c * 1024], acc[c], 0, 0, 0);
    }
    // C/D: col = lane&15, row = quad*4 + reg
#pragma unroll
    for (int i = 0; i < 4; ++i) {
        size_t base = (size_t)(m0 + quad * 4 + i) * 128 + r;
#pragma unroll
        for (int c = 0; c < 8; ++c)
            t2[base + c * 16] = __float2bfloat16(acc[c][i]);
    }
}

// ---------------- Layer 2 aggregate + fused layer-3 matmul ----------------
// wave per node; lane holds features {2*lane, 2*lane+1}; one coalesced 256B row per edge;
// epilogue: h2 = relu(di*acc + b2) stays in regs, reduce h2@W3 across the wave -> t3[N,2]

__global__ __launch_bounds__(256) void k_agg2(const uint* __restrict__ t2u,
                       const float* __restrict__ dinv,
                       const int* __restrict__ row_ptr, const int2* __restrict__ ew,
                       const float* __restrict__ b2, const float* __restrict__ W3,
                       float2* __restrict__ t3, int n) {
    int node = blockIdx.x * 4 + (threadIdx.x >> 6);
    if (node >= n) return;
    int lane = threadIdx.x & 63;
    float di = dinv[node];
    float2 p = up_bf2(t2u[(size_t)node * 64 + lane]);
    float a0 = di * p.x, a1 = di * p.y;  // self-loop
    int e0 = row_ptr[node], e1 = row_ptr[node + 1];
    int e = e0;
    for (; e + 4 <= e1; e += 4) {
        int2 w0 = ew[e], w1 = ew[e + 1], w2 = ew[e + 2], w3 = ew[e + 3];
        uint r0 = t2u[(size_t)w0.x * 64 + lane];
        uint r1 = t2u[(size_t)w1.x * 64 + lane];
        uint r2 = t2u[(size_t)w2.x * 64 + lane];
        uint r3 = t2u[(size_t)w3.x * 64 + lane];
        float2 q0 = up_bf2(r0), q1 = up_bf2(r1), q2 = up_bf2(r2), q3 = up_bf2(r3);
        a0 += __int_as_float(w0.y) * q0.x + __int_as_float(w1.y) * q1.x
            + __int_as_float(w2.y) * q2.x + __int_as_float(w3.y) * q3.x;
        a1 += __int_as_float(w0.y) * q0.y + __int_as_float(w1.y) * q1.y
            + __int_as_float(w2.y) * q2.y + __int_as_float(w3.y) * q3.y;
    }
    for (; e < e1; ++e) {
        int2 w0 = ew[e];
        float2 q0 = up_bf2(t2u[(size_t)w0.x * 64 + lane]);
        a0 += __int_as_float(w0.y) * q0.x;
        a1 += __int_as_float(w0.y) * q0.y;
    }
    float2 bb = *reinterpret_cast<const float2*>(b2 + 2 * lane);
    float h0 = fmaxf(di * a0 + bb.x, 0.f);
    float h1v = fmaxf(di * a1 + bb.y, 0.f);
    // t3 partials: W3 rows 2*lane, 2*lane+1 -> contiguous float4
    float4 wv = *reinterpret_cast<const float4*>(W3 + 4 * lane);
    float c0 = h0 * wv.x + h1v * wv.z;
    float c1 = h0 * wv.y + h1v * wv.w;
#pragma unroll
    for (int off = 32; off; off >>= 1) {
        c0 += __shfl_xor(c0, off);
        c1 += __shfl_xor(c1, off);
    }
    if (lane == 0) t3[node] = make_float2(c0, c1);
}

// ---------------- Layer 3 aggregate + log_softmax ----------------

__global__ void k_agg3(const float2* __restrict__ t3, const float* __restrict__ dinv,
                       const int* __restrict__ row_ptr, const int2* __restrict__ ew,
                       const float* __restrict__ b3, float2* __restrict__ outv, int n) {
    int node = blockIdx.x * blockDim.x + threadIdx.x;
    if (node >= n) return;
    float di = dinv[node];
    float2 s = t3[node];
    float a0 = di * s.x, a1 = di * s.y;
    int e0 = row_ptr[node], e1 = row_ptr[node + 1];
    int e = e0;
    for (; e + 4 <= e1; e += 4) {
        int2 w0 = ew[e], w1 = ew[e + 1], w2 = ew[e + 2], w3 = ew[e + 3];
        float2 q0 = t3[w0.x], q1 = t3[w1.x], q2 = t3[w2.x], q3 = t3[w3.x];
        a0 += __int_as_float(w0.y) * q0.x + __int_as_float(w1.y) * q1.x
            + __int_as_float(w2.y) * q2.x + __int_as_float(w3.y) * q3.x;
        a1 += __int_as_float(w0.y) * q0.y + __int_as_float(w1.y) * q1.y
            + __int_as_float(w2.y) * q2.y + __int_as_float(w3.y) * q3.y;
    }
    for (; e < e1; ++e) {
        int2 w0 = ew[e];
        float2 q0 = t3[w0.x];
        a0 += __int_as_float(w0.y) * q0.x;
        a1 += __int_as_float(w0.y) * q0.y;
    }
    float z0 = di * a0 + b3[0];
    float z1 = di * a1 + b3[1];
    float m = fmaxf(z0, z1);
    float lse = m + logf(expf(z0 - m) + expf(z1 - m));
    outv[node] = make_float2(z0 - lse, z1 - lse);
}

// ---------------- launch ----------------

extern "C" void kernel_launch(void* const* d_in, const int* in_sizes, int n_in,
                              void* d_out, int out_size, void* d_ws, size_t ws_size,
                              hipStream_t stream) {
    const float* x  = (const float*)d_in[0];
    const float* W1 = (const float*)d_in[1];
    const float* b1 = (const float*)d_in[2];
    const float* W2 = (const float*)d_in[3];
    const float* b2 = (const float*)d_in[4];
    const float* W3 = (const float*)d_in[5];
    const float* b3 = (const float*)d_in[6];
    const int* edges = (const int*)d_in[7];

    int n = in_sizes[0] / 9;
    int E = in_sizes[7] / 2;
    const int* src = edges;
    const int* dst = edges + E;

    char* p = (char*)d_ws;
    auto alloc = [&](size_t bytes) {
        char* q = p;
        p += (bytes + 511) & ~(size_t)511;
        return q;
    };
    int*   deg     = (int*)alloc((size_t)n * 4);
    float* dinv    = (float*)alloc((size_t)n * 4);
    int*   incl    = (int*)alloc((size_t)n * 4);
    int*   bsum    = (int*)alloc(4096);
    int*   row_ptr = (int*)alloc((size_t)(n + 1) * 4);
    int*   cursor  = (int*)alloc((size_t)n * 4);
    int2*  ew      = (int2*)alloc((size_t)E * 8);
    float* aggx    = (float*)alloc((size_t)n * 9 * 4);
    __hip_bfloat16* h1  = (__hip_bfloat16*)alloc((size_t)n * 512 * 2);
    __hip_bfloat16* W2t = (__hip_bfloat16*)alloc(512 * 128 * 2);
    __hip_bfloat16* t2  = (__hip_bfloat16*)alloc((size_t)n * 128 * 2);
    float2* t3 = (float2*)alloc((size_t)n * 8);

    const int B = 256;
    hipMemsetAsync(deg, 0, (size_t)n * 4, stream);
    k_degree<<<(E + B - 1) / B, B, 0, stream>>>(dst, deg, E);
    k_dinv<<<(n + B - 1) / B, B, 0, stream>>>(deg, dinv, n);
    int nb = (n + 1023) / 1024;
    k_scan1<<<nb, 1024, 0, stream>>>(deg, incl, bsum, n);
    k_scan2<<<1, 1024, 0, stream>>>(bsum, nb);
    k_scan3<<<(n + B - 1) / B, B, 0, stream>>>(incl, deg, bsum, row_ptr, cursor, n);
    k_csr<<<(E + B - 1) / B, B, 0, stream>>>(src, dst, dinv, cursor, ew, E);

    k_agg1<<<(n + 15) / 16, B, 0, stream>>>(x, dinv, row_ptr, ew, aggx, n);
    k_l1mm<<<(n * 64 + B - 1) / B, B, 0, stream>>>(aggx, W1, b1, h1, n);

    k_w2t<<<(512 * 128 + B - 1) / B, B, 0, stream>>>(W2, W2t);
    k_l2mm<<<(n / 16 + 3) / 4, 256, 0, stream>>>(h1, W2t, t2, n);
    k_agg2<<<(n + 3) / 4, 256, 0, stream>>>((const uint*)t2, dinv, row_ptr, ew, b2, W3, t3, n);

    k_agg3<<<(n + B - 1) / B, B, 0, stream>>>(t3, dinv, row_ptr, ew, b3, (float2*)d_out, n);
}